// Round 2
// baseline (1148.969 us; speedup 1.0000x reference)
//
#include <hip/hip_runtime.h>
#include <hip/hip_bf16.h>

#define NB 8
#define NN 2048
#define DD 128

// ---------------- Kernel 1: hp = h @ W + b_proj ----------------
// 256 blocks x 64 rows. K split in 2 passes so static LDS stays < 64KB.
__global__ __launch_bounds__(256) void proj_kernel(
    const float* __restrict__ h, const float* __restrict__ W,
    const float* __restrict__ bias, float* __restrict__ hp)
{
    __shared__ float Ws[64][132];   // 33.8 KB  (K-half of W, padded)
    __shared__ float hs[64][68];    // 17.4 KB  (row-tile, K-half, padded)
    const int tid = threadIdx.x;
    const int rowbase = blockIdx.x * 64;
    const int rg = tid >> 3;        // 0..31 -> rows 2rg, 2rg+1
    const int dg = tid & 7;         // dims dg*16 .. dg*16+15

    const float4* W4 = (const float4*)W;
    const float4* h4 = (const float4*)h;

    float acc[2][16];
    #pragma unroll
    for (int r = 0; r < 2; ++r)
        #pragma unroll
        for (int d = 0; d < 16; ++d) acc[r][d] = 0.f;

    for (int p = 0; p < 2; ++p) {
        // stage W[64p..64p+63][0..127] : 2048 float4
        #pragma unroll
        for (int q = 0; q < 8; ++q) {
            int f = tid + 256 * q;
            float4 v = W4[2048 * p + f];
            *(float4*)&Ws[f >> 5][4 * (f & 31)] = v;
        }
        // stage h[rowbase..+63][64p..64p+63] : 1024 float4
        #pragma unroll
        for (int q = 0; q < 4; ++q) {
            int f = tid + 256 * q;
            int r = f >> 4, c4 = f & 15;
            float4 v = h4[(size_t)(rowbase + r) * 32 + 16 * p + c4];
            *(float4*)&hs[r][4 * c4] = v;
        }
        __syncthreads();

        #pragma unroll 8
        for (int k = 0; k < 64; ++k) {
            float h0 = hs[2 * rg][k];
            float h1 = hs[2 * rg + 1][k];
            float4 w0 = *(const float4*)&Ws[k][dg * 16];
            float4 w1 = *(const float4*)&Ws[k][dg * 16 + 4];
            float4 w2 = *(const float4*)&Ws[k][dg * 16 + 8];
            float4 w3 = *(const float4*)&Ws[k][dg * 16 + 12];
            float wv[16] = {w0.x,w0.y,w0.z,w0.w, w1.x,w1.y,w1.z,w1.w,
                            w2.x,w2.y,w2.z,w2.w, w3.x,w3.y,w3.z,w3.w};
            #pragma unroll
            for (int d = 0; d < 16; ++d) {
                acc[0][d] += h0 * wv[d];
                acc[1][d] += h1 * wv[d];
            }
        }
        __syncthreads();
    }

    const float4* b4 = (const float4*)bias;
    float4 bv[4];
    #pragma unroll
    for (int dq = 0; dq < 4; ++dq) bv[dq] = b4[dg * 4 + dq];
    #pragma unroll
    for (int r = 0; r < 2; ++r) {
        int row = rowbase + 2 * rg + r;
        float4* o = (float4*)(hp + (size_t)row * 128);
        #pragma unroll
        for (int dq = 0; dq < 4; ++dq) {
            float4 v;
            v.x = acc[r][4 * dq + 0] + bv[dq].x;
            v.y = acc[r][4 * dq + 1] + bv[dq].y;
            v.z = acc[r][4 * dq + 2] + bv[dq].z;
            v.w = acc[r][4 * dq + 3] + bv[dq].w;
            o[dg * 4 + dq] = v;
        }
    }
}

// ---------------- Kernel 2: s = hp.w_src ; t = hp.w_dst ----------------
__global__ __launch_bounds__(256) void rowdot_kernel(
    const float* __restrict__ hp, const float* __restrict__ watt,
    float* __restrict__ s, float* __restrict__ t)
{
    int row  = blockIdx.x * 4 + (threadIdx.x >> 6);
    int lane = threadIdx.x & 63;
    const float* hr = hp + (size_t)row * 128;
    float v0 = hr[lane], v1 = hr[lane + 64];
    float sp = v0 * watt[lane]       + v1 * watt[lane + 64];
    float tp = v0 * watt[128 + lane] + v1 * watt[192 + lane];
    #pragma unroll
    for (int m = 32; m >= 1; m >>= 1) {
        sp += __shfl_xor(sp, m, 64);
        tp += __shfl_xor(tp, m, 64);
    }
    if (lane == 0) { s[row] = sp; t[row] = tp; }
}

// ---------------- Kernel 3: fused  exp(relu(s_i+t_j+b))*a, row-norm, @hp, +hp ----
// 512 blocks (= B * N/32), 256 threads (4 waves), 32 rows/block, j-tiles of 64.
// Phase B: 8 rows x 8 dims per thread, 4-way j-split with persistent partial acc.
// LDS 51.3 KB -> 2 blocks/CU.
__global__ __launch_bounds__(256, 2) void fused_kernel(
    const float* __restrict__ a, const float* __restrict__ hp,
    const float* __restrict__ s, const float* __restrict__ t,
    const float* __restrict__ battp, float* __restrict__ out)
{
    __shared__ float w_s[2][64][36];   // transposed: [j][i], stride 36 (16B-aligned)
    __shared__ float hp_s[64][128];    // single-buffered j-tile of hp
    __shared__ float wsum_s[32];

    const int tid = threadIdx.x;
    const int b = blockIdx.x >> 6;
    const int ibase = (blockIdx.x & 63) * 32;
    const int bN = b * NN;

    // phase A mapping
    const int cA = tid & 15;           // j-quad 4cA..4cA+3
    const int gA = tid >> 4;           // rows gA, gA+16
    // phase B mapping
    const int dg8 = (tid & 15) * 8;    // dims dg8..dg8+7
    const int rg8 = ((tid >> 4) & 3) * 8;  // rows rg8..rg8+7
    const int jh = tid >> 6;           // j-quarter (== wave id)
    const int jh16 = jh * 16;

    const float batt = battp[0];
    const float4* a4  = (const float4*)a;
    const float4* hp4 = (const float4*)hp;
    const float4* t4  = (const float4*)t;
    float4* out4 = (float4*)out;

    float s_reg[2];
    #pragma unroll
    for (int ri = 0; ri < 2; ++ri)
        s_reg[ri] = s[bN + ibase + gA + 16 * ri];

    float wsum_p[2] = {0.f, 0.f};
    float acc[8][8];
    #pragma unroll
    for (int r = 0; r < 8; ++r)
        #pragma unroll
        for (int d = 0; d < 8; ++d) acc[r][d] = 0.f;

    float4 a_nx[2], h_nx[8], t_nx;

    auto LOAD = [&](int tt) {
        int jq = tt * 16;
        #pragma unroll
        for (int ri = 0; ri < 2; ++ri)
            a_nx[ri] = a4[(size_t)(bN + ibase + gA + 16 * ri) * 512 + jq + cA];
        t_nx = t4[(bN >> 2) + jq + cA];
        #pragma unroll
        for (int q = 0; q < 8; ++q) {
            int f = tid + 256 * q;
            int jr = f >> 5, c4 = f & 31;
            h_nx[q] = hp4[(size_t)(bN + tt * 64 + jr) * 32 + c4];
        }
    };
    auto STOREHP = [&]() {
        #pragma unroll
        for (int q = 0; q < 8; ++q) {
            int f = tid + 256 * q;
            int jr = f >> 5, c4 = f & 31;
            *(float4*)&hp_s[jr][4 * c4] = h_nx[q];
        }
    };
    auto PHASEA = [&](int buf) {
        #pragma unroll
        for (int ri = 0; ri < 2; ++ri) {
            float av[4] = {a_nx[ri].x, a_nx[ri].y, a_nx[ri].z, a_nx[ri].w};
            float tv[4] = {t_nx.x, t_nx.y, t_nx.z, t_nx.w};
            #pragma unroll
            for (int k = 0; k < 4; ++k) {
                float e = fmaxf(s_reg[ri] + tv[k] + batt, 0.f);
                float p = __expf(e) * av[k];
                wsum_p[ri] += p;
                w_s[buf][4 * cA + k][gA + 16 * ri] = p;
            }
        }
    };
    auto PHASEB = [&](int cur) {
        #pragma unroll
        for (int jj = 0; jj < 16; ++jj) {
            int j = jh16 + jj;
            float4 wa = *(const float4*)&w_s[cur][j][rg8];
            float4 wb = *(const float4*)&w_s[cur][j][rg8 + 4];
            float4 ha = *(const float4*)&hp_s[j][dg8];
            float4 hb = *(const float4*)&hp_s[j][dg8 + 4];
            float wv[8] = {wa.x,wa.y,wa.z,wa.w, wb.x,wb.y,wb.z,wb.w};
            float hv[8] = {ha.x,ha.y,ha.z,ha.w, hb.x,hb.y,hb.z,hb.w};
            #pragma unroll
            for (int r = 0; r < 8; ++r)
                #pragma unroll
                for (int d = 0; d < 8; ++d)
                    acc[r][d] += wv[r] * hv[d];
        }
    };

    LOAD(0);
    STOREHP();
    PHASEA(0);
    __syncthreads();

    for (int tt = 0; tt < 32; ++tt) {
        const int cur = tt & 1;
        if (tt < 31) LOAD(tt + 1);       // global->reg prefetch, in flight during B
        PHASEB(cur);
        __syncthreads();                 // all reads of hp_s / w_s[cur] done
        if (tt < 31) {
            STOREHP();
            PHASEA(cur ^ 1);
            __syncthreads();             // LDS writes visible for next PHASEB
        }
    }

    // ---- row-sum reduce (across cA within each 16-lane group) ----
    #pragma unroll
    for (int ri = 0; ri < 2; ++ri) {
        float v = wsum_p[ri];
        v += __shfl_xor(v, 1, 64);
        v += __shfl_xor(v, 2, 64);
        v += __shfl_xor(v, 4, 64);
        v += __shfl_xor(v, 8, 64);
        if (cA == 0) wsum_s[gA + 16 * ri] = v;
    }

    // ---- cross-jh tree reduction of acc (reuse hp_s as red[2][32][128]) ----
    float (*red)[32][128] = (float (*)[32][128])hp_s;
    __syncthreads();   // ensure last PHASEB reads done before overwriting hp_s
    if (jh >= 2) {
        #pragma unroll
        for (int r = 0; r < 8; ++r)
            #pragma unroll
            for (int d = 0; d < 8; ++d)
                red[jh - 2][rg8 + r][dg8 + d] = acc[r][d];
    }
    __syncthreads();
    if (jh < 2) {
        #pragma unroll
        for (int r = 0; r < 8; ++r)
            #pragma unroll
            for (int d = 0; d < 8; ++d)
                acc[r][d] += red[jh][rg8 + r][dg8 + d];
    }
    __syncthreads();
    if (jh == 1) {
        #pragma unroll
        for (int r = 0; r < 8; ++r)
            #pragma unroll
            for (int d = 0; d < 8; ++d)
                red[0][rg8 + r][dg8 + d] = acc[r][d];
    }
    __syncthreads();

    if (jh == 0) {
        #pragma unroll
        for (int r = 0; r < 8; ++r) {
            int row = rg8 + r;
            float inv = 1.0f / wsum_s[row];
            size_t gr = (size_t)(bN + ibase + row);
            float4 h0 = hp4[gr * 32 + (dg8 >> 2)];
            float4 h1 = hp4[gr * 32 + (dg8 >> 2) + 1];
            float r0 = red[0][row][dg8 + 0], r1 = red[0][row][dg8 + 1];
            float r2 = red[0][row][dg8 + 2], r3 = red[0][row][dg8 + 3];
            float r4 = red[0][row][dg8 + 4], r5 = red[0][row][dg8 + 5];
            float r6 = red[0][row][dg8 + 6], r7 = red[0][row][dg8 + 7];
            float4 o0, o1;
            o0.x = (acc[r][0] + r0) * inv + h0.x;
            o0.y = (acc[r][1] + r1) * inv + h0.y;
            o0.z = (acc[r][2] + r2) * inv + h0.z;
            o0.w = (acc[r][3] + r3) * inv + h0.w;
            o1.x = (acc[r][4] + r4) * inv + h1.x;
            o1.y = (acc[r][5] + r5) * inv + h1.y;
            o1.z = (acc[r][6] + r6) * inv + h1.z;
            o1.w = (acc[r][7] + r7) * inv + h1.w;
            out4[gr * 32 + (dg8 >> 2)]     = o0;
            out4[gr * 32 + (dg8 >> 2) + 1] = o1;
        }
    }
}

extern "C" void kernel_launch(void* const* d_in, const int* in_sizes, int n_in,
                              void* d_out, int out_size, void* d_ws, size_t ws_size,
                              hipStream_t stream) {
    const float* a      = (const float*)d_in[0];   // [B,N,N]
    const float* h      = (const float*)d_in[1];   // [B,N,128]
    const float* W_proj = (const float*)d_in[2];   // [128,128]
    const float* b_proj = (const float*)d_in[3];   // [128]
    const float* w_att  = (const float*)d_in[4];   // [256]
    const float* b_att  = (const float*)d_in[5];   // [1]
    float* out = (float*)d_out;

    float* hp = (float*)d_ws;                          // [B*N,128]
    float* s  = hp + (size_t)NB * NN * DD;             // [B*N]
    float* t  = s + (size_t)NB * NN;                   // [B*N]

    proj_kernel<<<256, 256, 0, stream>>>(h, W_proj, b_proj, hp);
    rowdot_kernel<<<4096, 256, 0, stream>>>(hp, w_att, s, t);
    fused_kernel<<<512, 256, 0, stream>>>(a, hp, s, t, b_att, out);
}

// Round 3
// 307.610 us; speedup vs baseline: 3.7351x; 3.7351x over previous
//
#include <hip/hip_runtime.h>
#include <hip/hip_bf16.h>

#define NB 8
#define NN 2048
#define DD 128
#define WST 36   // w_s row stride (floats)

__device__ __forceinline__ void gll16(const void* g, void* l) {
    __builtin_amdgcn_global_load_lds(
        (const __attribute__((address_space(1))) void*)g,
        (__attribute__((address_space(3))) void*)l, 16, 0, 0);
}

// ---------- Kernel 1: hp = h@W + b ; s = hp.w_src ; t = hp.w_dst ----------
__global__ __launch_bounds__(256) void proj_kernel(
    const float* __restrict__ h, const float* __restrict__ W,
    const float* __restrict__ bias, const float* __restrict__ watt,
    float* __restrict__ hp, float* __restrict__ s, float* __restrict__ t)
{
    __shared__ float Ws[64][132];
    __shared__ float hs[64][68];
    const int tid = threadIdx.x;
    const int rowbase = blockIdx.x * 64;
    const int rg = tid >> 3;        // rows 2rg, 2rg+1
    const int dg = tid & 7;         // dims dg*16..+15

    const float4* W4 = (const float4*)W;
    const float4* h4 = (const float4*)h;

    float acc[2][16];
    #pragma unroll
    for (int r = 0; r < 2; ++r)
        #pragma unroll
        for (int d = 0; d < 16; ++d) acc[r][d] = 0.f;

    for (int p = 0; p < 2; ++p) {
        #pragma unroll
        for (int q = 0; q < 8; ++q) {
            int f = tid + 256 * q;
            float4 v = W4[2048 * p + f];
            *(float4*)&Ws[f >> 5][4 * (f & 31)] = v;
        }
        #pragma unroll
        for (int q = 0; q < 4; ++q) {
            int f = tid + 256 * q;
            int r = f >> 4, c4 = f & 15;
            float4 v = h4[(size_t)(rowbase + r) * 32 + 16 * p + c4];
            *(float4*)&hs[r][4 * c4] = v;
        }
        __syncthreads();

        #pragma unroll 8
        for (int k = 0; k < 64; ++k) {
            float h0 = hs[2 * rg][k];
            float h1 = hs[2 * rg + 1][k];
            float4 w0 = *(const float4*)&Ws[k][dg * 16];
            float4 w1 = *(const float4*)&Ws[k][dg * 16 + 4];
            float4 w2 = *(const float4*)&Ws[k][dg * 16 + 8];
            float4 w3 = *(const float4*)&Ws[k][dg * 16 + 12];
            float wv[16] = {w0.x,w0.y,w0.z,w0.w, w1.x,w1.y,w1.z,w1.w,
                            w2.x,w2.y,w2.z,w2.w, w3.x,w3.y,w3.z,w3.w};
            #pragma unroll
            for (int d = 0; d < 16; ++d) {
                acc[0][d] += h0 * wv[d];
                acc[1][d] += h1 * wv[d];
            }
        }
        __syncthreads();
    }

    // bias into acc
    const float4* b4 = (const float4*)bias;
    #pragma unroll
    for (int dq = 0; dq < 4; ++dq) {
        float4 bv = b4[dg * 4 + dq];
        #pragma unroll
        for (int r = 0; r < 2; ++r) {
            acc[r][4 * dq + 0] += bv.x;
            acc[r][4 * dq + 1] += bv.y;
            acc[r][4 * dq + 2] += bv.z;
            acc[r][4 * dq + 3] += bv.w;
        }
    }
    // store hp
    #pragma unroll
    for (int r = 0; r < 2; ++r) {
        float4* o = (float4*)(hp + (size_t)(rowbase + 2 * rg + r) * 128);
        #pragma unroll
        for (int dq = 0; dq < 4; ++dq) {
            float4 v = {acc[r][4*dq+0], acc[r][4*dq+1], acc[r][4*dq+2], acc[r][4*dq+3]};
            o[dg * 4 + dq] = v;
        }
    }
    // rowdot: s,t
    const float4* w4 = (const float4*)watt;
    float sp[2] = {0.f, 0.f}, tp[2] = {0.f, 0.f};
    #pragma unroll
    for (int q = 0; q < 4; ++q) {
        float4 wsa = w4[dg * 4 + q];
        float4 wta = w4[32 + dg * 4 + q];
        #pragma unroll
        for (int r = 0; r < 2; ++r) {
            sp[r] += acc[r][4*q+0]*wsa.x + acc[r][4*q+1]*wsa.y
                   + acc[r][4*q+2]*wsa.z + acc[r][4*q+3]*wsa.w;
            tp[r] += acc[r][4*q+0]*wta.x + acc[r][4*q+1]*wta.y
                   + acc[r][4*q+2]*wta.z + acc[r][4*q+3]*wta.w;
        }
    }
    #pragma unroll
    for (int r = 0; r < 2; ++r) {
        float v = sp[r], u = tp[r];
        v += __shfl_xor(v, 1, 64); u += __shfl_xor(u, 1, 64);
        v += __shfl_xor(v, 2, 64); u += __shfl_xor(u, 2, 64);
        v += __shfl_xor(v, 4, 64); u += __shfl_xor(u, 4, 64);
        if (dg == 0) {
            s[rowbase + 2 * rg + r] = v;
            t[rowbase + 2 * rg + r] = u;
        }
    }
}

// ---------- Kernel 2: fused  w=exp(relu(s_i+t_j+b))*a, row-norm, @hp, +hp ----------
// 512 blocks (B x N/32), 256 thr. I=32 rows, JT=32 j-tile, 64 tiles.
// hp staged global->LDS direct (dbuf); w dbuf in LDS; 1 barrier/tile.
// Thread: 8 rows x 8 dims (dims {4dg..+3, 64+4dg..+3}), 4-way j-split.
__global__ __launch_bounds__(256, 2) void fused_kernel(
    const float* __restrict__ a, const float* __restrict__ hp,
    const float* __restrict__ s, const float* __restrict__ t,
    const float* __restrict__ battp, float* __restrict__ out)
{
    __shared__ float hp_s[2][32][128];   // 32 KB, linear (gll dest)
    __shared__ float w_s[2][32][WST];    // [j][i] transposed, 9.2 KB
    __shared__ float wsum_s[32];

    const int tid  = threadIdx.x;
    const int lane = tid & 63;
    const int wid  = tid >> 6;
    const int b     = blockIdx.x >> 6;
    const int ibase = (blockIdx.x & 63) * 32;
    const int bN    = b * NN;

    const int jqA  = tid & 7;            // phase A: j = 4*jqA..+3
    const int rowA = tid >> 3;           // phase A: row 0..31
    const int dg   = tid & 15;           // phase B: dims 4dg..+3, 64+4dg..+3
    const int rg8  = ((tid >> 4) & 3) * 8;
    const int jh   = wid;                // j-split group: j = jh*8 + jj

    const float batt = battp[0];
    const float4* a4  = (const float4*)a;
    const float4* t4  = (const float4*)t;
    const float4* hp4 = (const float4*)hp;
    float4* out4 = (float4*)out;

    const float s_reg = s[bN + ibase + rowA];
    const size_t arow = (size_t)(bN + ibase + rowA) * 512;

    float wsum_p = 0.f;
    float acc[8][8];
    #pragma unroll
    for (int r = 0; r < 8; ++r)
        #pragma unroll
        for (int d = 0; d < 8; ++d) acc[r][d] = 0.f;

    float4 a_nx, t_nx;

#define LOADA(tt) do { \
        a_nx = a4[arow + (tt) * 8 + jqA]; \
        t_nx = t4[(bN >> 2) + (tt) * 8 + jqA]; \
    } while (0)

#define GLL(tt, nb) do { \
        const float* gsrc = hp + (size_t)(bN + (tt) * 32) * 128 + wid * 1024 + lane * 4; \
        float* ldst = &hp_s[nb][0][0] + wid * 1024; \
        gll16(gsrc,       ldst); \
        gll16(gsrc + 256, ldst + 256); \
        gll16(gsrc + 512, ldst + 512); \
        gll16(gsrc + 768, ldst + 768); \
    } while (0)

#define PHASEA(nb) do { \
        float av[4] = {a_nx.x, a_nx.y, a_nx.z, a_nx.w}; \
        float tv[4] = {t_nx.x, t_nx.y, t_nx.z, t_nx.w}; \
        _Pragma("unroll") \
        for (int k = 0; k < 4; ++k) { \
            float e = fmaxf(s_reg + tv[k] + batt, 0.f); \
            float p = __expf(e) * av[k]; \
            wsum_p += p; \
            w_s[nb][4 * jqA + k][rowA] = p; \
        } \
    } while (0)

#define PHASEB(cb) do { \
        _Pragma("unroll") \
        for (int jj = 0; jj < 8; ++jj) { \
            int j = jh * 8 + jj; \
            float4 wa = *(const float4*)&w_s[cb][j][rg8]; \
            float4 wb = *(const float4*)&w_s[cb][j][rg8 + 4]; \
            float4 ha = *(const float4*)&hp_s[cb][j][4 * dg]; \
            float4 hb = *(const float4*)&hp_s[cb][j][64 + 4 * dg]; \
            float wv[8] = {wa.x,wa.y,wa.z,wa.w, wb.x,wb.y,wb.z,wb.w}; \
            float hv[8] = {ha.x,ha.y,ha.z,ha.w, hb.x,hb.y,hb.z,hb.w}; \
            _Pragma("unroll") \
            for (int r = 0; r < 8; ++r) \
                _Pragma("unroll") \
                for (int d = 0; d < 8; ++d) \
                    acc[r][d] += wv[r] * hv[d]; \
        } \
    } while (0)

    // prologue: tile 0 staged into buf 0
    GLL(0, 0);
    LOADA(0);
    PHASEA(0);
    LOADA(1);
    __syncthreads();

    int cur = 0;
    for (int tt = 0; tt < 64; ++tt) {
        if (tt < 63) {
            GLL(tt + 1, cur ^ 1);          // async, lands by next barrier
            PHASEA(cur ^ 1);               // w for tile tt+1 (disjoint buffer)
            if (tt < 62) LOADA(tt + 2);    // refill a/t prefetch regs
        }
        PHASEB(cur);
        __syncthreads();
        cur ^= 1;
    }

    // row-sum reduce across the 8 jqA lanes sharing a row
    {
        float v = wsum_p;
        v += __shfl_xor(v, 1, 64);
        v += __shfl_xor(v, 2, 64);
        v += __shfl_xor(v, 4, 64);
        if (jqA == 0) wsum_s[rowA] = v;
    }

    // 4-way acc tree reduction across jh (reuse hp_s as red[2][32][128])
    float (*red)[32][128] = (float (*)[32][128])hp_s;
    if (jh >= 2) {
        #pragma unroll
        for (int r = 0; r < 8; ++r) {
            float4 v0 = {acc[r][0], acc[r][1], acc[r][2], acc[r][3]};
            float4 v1 = {acc[r][4], acc[r][5], acc[r][6], acc[r][7]};
            *(float4*)&red[jh - 2][rg8 + r][4 * dg]      = v0;
            *(float4*)&red[jh - 2][rg8 + r][64 + 4 * dg] = v1;
        }
    }
    __syncthreads();
    if (jh < 2) {
        #pragma unroll
        for (int r = 0; r < 8; ++r) {
            float4 v0 = *(const float4*)&red[jh][rg8 + r][4 * dg];
            float4 v1 = *(const float4*)&red[jh][rg8 + r][64 + 4 * dg];
            acc[r][0] += v0.x; acc[r][1] += v0.y; acc[r][2] += v0.z; acc[r][3] += v0.w;
            acc[r][4] += v1.x; acc[r][5] += v1.y; acc[r][6] += v1.z; acc[r][7] += v1.w;
        }
    }
    __syncthreads();
    if (jh == 1) {
        #pragma unroll
        for (int r = 0; r < 8; ++r) {
            float4 v0 = {acc[r][0], acc[r][1], acc[r][2], acc[r][3]};
            float4 v1 = {acc[r][4], acc[r][5], acc[r][6], acc[r][7]};
            *(float4*)&red[0][rg8 + r][4 * dg]      = v0;
            *(float4*)&red[0][rg8 + r][64 + 4 * dg] = v1;
        }
    }
    __syncthreads();
    if (jh == 0) {
        #pragma unroll
        for (int r = 0; r < 8; ++r) {
            int row = rg8 + r;
            float inv = 1.0f / wsum_s[row];
            size_t gr = (size_t)(bN + ibase + row);
            float4 r0 = *(const float4*)&red[0][row][4 * dg];
            float4 r1 = *(const float4*)&red[0][row][64 + 4 * dg];
            float4 h0 = hp4[gr * 32 + dg];
            float4 h1 = hp4[gr * 32 + 16 + dg];
            float4 o0, o1;
            o0.x = (acc[r][0] + r0.x) * inv + h0.x;
            o0.y = (acc[r][1] + r0.y) * inv + h0.y;
            o0.z = (acc[r][2] + r0.z) * inv + h0.z;
            o0.w = (acc[r][3] + r0.w) * inv + h0.w;
            o1.x = (acc[r][4] + r1.x) * inv + h1.x;
            o1.y = (acc[r][5] + r1.y) * inv + h1.y;
            o1.z = (acc[r][6] + r1.z) * inv + h1.z;
            o1.w = (acc[r][7] + r1.w) * inv + h1.w;
            out4[gr * 32 + dg]      = o0;
            out4[gr * 32 + 16 + dg] = o1;
        }
    }
}

extern "C" void kernel_launch(void* const* d_in, const int* in_sizes, int n_in,
                              void* d_out, int out_size, void* d_ws, size_t ws_size,
                              hipStream_t stream) {
    const float* a      = (const float*)d_in[0];   // [B,N,N]
    const float* h      = (const float*)d_in[1];   // [B,N,128]
    const float* W_proj = (const float*)d_in[2];   // [128,128]
    const float* b_proj = (const float*)d_in[3];   // [128]
    const float* w_att  = (const float*)d_in[4];   // [256]
    const float* b_att  = (const float*)d_in[5];   // [1]
    float* out = (float*)d_out;

    float* hp = (float*)d_ws;                      // [B*N,128]
    float* s  = hp + (size_t)NB * NN * DD;         // [B*N]
    float* t  = s + (size_t)NB * NN;               // [B*N]

    proj_kernel<<<256, 256, 0, stream>>>(h, W_proj, b_proj, w_att, hp, s, t);
    fused_kernel<<<512, 256, 0, stream>>>(a, hp, s, t, b_att, out);
}

// Round 4
// 264.259 us; speedup vs baseline: 4.3479x; 1.1640x over previous
//
#include <hip/hip_runtime.h>
#include <hip/hip_bf16.h>

#define NB 8
#define NN 2048
#define DD 128
#define NT 32    // 32 j-tiles of 64

typedef __attribute__((ext_vector_type(8))) short short8v;
typedef __attribute__((ext_vector_type(4))) float f32x4;

__device__ __forceinline__ unsigned short f2bf(float x) {
    unsigned int u = __float_as_uint(x);
    u += 0x7FFFu + ((u >> 16) & 1u);
    return (unsigned short)(u >> 16);
}

// ---------- Kernel 1: hp = h@W + b ; s,t row-dots ; hpT = bf16 transpose ----------
__global__ __launch_bounds__(256) void proj_kernel(
    const float* __restrict__ h, const float* __restrict__ W,
    const float* __restrict__ bias, const float* __restrict__ watt,
    float* __restrict__ hp, unsigned short* __restrict__ hpT,
    float* __restrict__ s, float* __restrict__ t)
{
    __shared__ float Ws[64][132];
    __shared__ float hs[64][68];
    const int tid = threadIdx.x;
    const int rowbase = blockIdx.x * 64;
    const int rg = tid >> 3;        // rows 2rg, 2rg+1
    const int dg = tid & 7;         // dims dg*16..+15

    const float4* W4 = (const float4*)W;
    const float4* h4 = (const float4*)h;

    float acc[2][16];
    #pragma unroll
    for (int r = 0; r < 2; ++r)
        #pragma unroll
        for (int d = 0; d < 16; ++d) acc[r][d] = 0.f;

    for (int p = 0; p < 2; ++p) {
        #pragma unroll
        for (int q = 0; q < 8; ++q) {
            int f = tid + 256 * q;
            float4 v = W4[2048 * p + f];
            *(float4*)&Ws[f >> 5][4 * (f & 31)] = v;
        }
        #pragma unroll
        for (int q = 0; q < 4; ++q) {
            int f = tid + 256 * q;
            int r = f >> 4, c4 = f & 15;
            float4 v = h4[(size_t)(rowbase + r) * 32 + 16 * p + c4];
            *(float4*)&hs[r][4 * c4] = v;
        }
        __syncthreads();

        #pragma unroll 8
        for (int k = 0; k < 64; ++k) {
            float h0 = hs[2 * rg][k];
            float h1 = hs[2 * rg + 1][k];
            float4 w0 = *(const float4*)&Ws[k][dg * 16];
            float4 w1 = *(const float4*)&Ws[k][dg * 16 + 4];
            float4 w2 = *(const float4*)&Ws[k][dg * 16 + 8];
            float4 w3 = *(const float4*)&Ws[k][dg * 16 + 12];
            float wv[16] = {w0.x,w0.y,w0.z,w0.w, w1.x,w1.y,w1.z,w1.w,
                            w2.x,w2.y,w2.z,w2.w, w3.x,w3.y,w3.z,w3.w};
            #pragma unroll
            for (int d = 0; d < 16; ++d) {
                acc[0][d] += h0 * wv[d];
                acc[1][d] += h1 * wv[d];
            }
        }
        __syncthreads();
    }

    // bias
    const float4* b4 = (const float4*)bias;
    #pragma unroll
    for (int dq = 0; dq < 4; ++dq) {
        float4 bv = b4[dg * 4 + dq];
        #pragma unroll
        for (int r = 0; r < 2; ++r) {
            acc[r][4 * dq + 0] += bv.x;
            acc[r][4 * dq + 1] += bv.y;
            acc[r][4 * dq + 2] += bv.z;
            acc[r][4 * dq + 3] += bv.w;
        }
    }
    // store hp (f32)
    #pragma unroll
    for (int r = 0; r < 2; ++r) {
        float4* o = (float4*)(hp + (size_t)(rowbase + 2 * rg + r) * 128);
        #pragma unroll
        for (int dq = 0; dq < 4; ++dq) {
            float4 v = {acc[r][4*dq+0], acc[r][4*dq+1], acc[r][4*dq+2], acc[r][4*dq+3]};
            o[dg * 4 + dq] = v;
        }
    }
    // store hpT (bf16, transposed [b][d][j]); u32 packs j-pair (2rg, 2rg+1)
    {
        int rowpair = ((rowbase & (NN - 1)) >> 1) + rg;
        int bb = rowbase >> 11;
        unsigned int* hT32 = (unsigned int*)hpT;
        #pragma unroll
        for (int dd = 0; dd < 16; ++dd) {
            int d = dg * 16 + dd;
            unsigned int pk = (unsigned int)f2bf(acc[0][dd]) |
                              ((unsigned int)f2bf(acc[1][dd]) << 16);
            hT32[(((size_t)bb * 128 + d) << 10) + rowpair] = pk;
        }
    }
    // rowdot: s,t
    const float4* w4 = (const float4*)watt;
    float sp[2] = {0.f, 0.f}, tp[2] = {0.f, 0.f};
    #pragma unroll
    for (int q = 0; q < 4; ++q) {
        float4 wsa = w4[dg * 4 + q];
        float4 wta = w4[32 + dg * 4 + q];
        #pragma unroll
        for (int r = 0; r < 2; ++r) {
            sp[r] += acc[r][4*q+0]*wsa.x + acc[r][4*q+1]*wsa.y
                   + acc[r][4*q+2]*wsa.z + acc[r][4*q+3]*wsa.w;
            tp[r] += acc[r][4*q+0]*wta.x + acc[r][4*q+1]*wta.y
                   + acc[r][4*q+2]*wta.z + acc[r][4*q+3]*wta.w;
        }
    }
    #pragma unroll
    for (int r = 0; r < 2; ++r) {
        float v = sp[r], u = tp[r];
        v += __shfl_xor(v, 1, 64); u += __shfl_xor(u, 1, 64);
        v += __shfl_xor(v, 2, 64); u += __shfl_xor(u, 2, 64);
        v += __shfl_xor(v, 4, 64); u += __shfl_xor(u, 4, 64);
        if (dg == 0) {
            s[rowbase + 2 * rg + r] = v;
            t[rowbase + 2 * rg + r] = u;
        }
    }
}

// ---------- Kernel 2: fused  w=exp(relu(s_i+t_j+b))*a -> bf16 MFMA @hp, row-norm, +hp ----
// 1024 blocks (B x N/16), 256 thr (4 waves). 16 rows/block, JT=64, 32 tiles.
// LDS (swizzled, dbuf): hpT tile [128][64] bf16 + w tile [16][64] bf16 = 37 KB.
// Per wave: dims [32w..32w+32), 2 N-tiles x 2 K-steps -> 4 MFMA/tile, acc f32x4 x2.
__global__ __launch_bounds__(256, 4) void fused_kernel(
    const float* __restrict__ a, const float* __restrict__ hp,
    const unsigned short* __restrict__ hpT,
    const float* __restrict__ s, const float* __restrict__ t,
    const float* __restrict__ battp, float* __restrict__ out)
{
    __shared__ unsigned short hpT_s[2][128 * 64];
    __shared__ unsigned short w_s[2][16 * 64];
    __shared__ float wsum_s[16];

    const int tid  = threadIdx.x;
    const int lane = tid & 63;
    const int wv   = tid >> 6;
    const int b     = blockIdx.x >> 7;
    const int ibase = (blockIdx.x & 127) * 16;
    const int bN    = b * NN;

    const int rowA = tid >> 4;          // phase A row 0..15
    const int q    = tid & 15;          // phase A j-quad: j = 4q..4q+3
    const int sd   = tid >> 1;          // stage: d row 0..127
    const int sj   = (tid & 1) * 64;    // stage: j byte base within row

    const float batt = battp[0];
    const float4* a4 = (const float4*)a;
    const float4* t4 = (const float4*)t;
    const float s_reg = s[bN + ibase + rowA];
    const size_t arow = (size_t)(bN + ibase + rowA) * 512;
    const unsigned short* hTg = hpT + (((size_t)(b * 128 + sd)) << 11) + (tid & 1) * 32;

    float wsum_p = 0.f;
    f32x4 acc0 = {0.f, 0.f, 0.f, 0.f};
    f32x4 acc1 = {0.f, 0.f, 0.f, 0.f};

    float4 a_nx, t_nx;
    uint4 hv0, hv1, hv2, hv3;

#define LOADA(tt) do { \
        a_nx = a4[arow + (tt) * 16 + q]; \
        t_nx = t4[(bN >> 2) + (tt) * 16 + q]; \
    } while (0)

#define STAGELOAD(tt) do { \
        const unsigned short* gp = hTg + (tt) * 64; \
        hv0 = *(const uint4*)(gp);      hv1 = *(const uint4*)(gp + 8); \
        hv2 = *(const uint4*)(gp + 16); hv3 = *(const uint4*)(gp + 24); \
    } while (0)

#define STAGEWRITE(nb) do { \
        char* lb = (char*)hpT_s[nb]; \
        int swz = (sd & 7) << 4; \
        int bo = (sd << 7) + sj; \
        *(uint4*)(lb + ((bo     ) ^ swz)) = hv0; \
        *(uint4*)(lb + ((bo + 16) ^ swz)) = hv1; \
        *(uint4*)(lb + ((bo + 32) ^ swz)) = hv2; \
        *(uint4*)(lb + ((bo + 48) ^ swz)) = hv3; \
    } while (0)

#define PHASEA(nb) do { \
        float p0 = __expf(fmaxf(s_reg + t_nx.x + batt, 0.f)) * a_nx.x; \
        float p1 = __expf(fmaxf(s_reg + t_nx.y + batt, 0.f)) * a_nx.y; \
        float p2 = __expf(fmaxf(s_reg + t_nx.z + batt, 0.f)) * a_nx.z; \
        float p3 = __expf(fmaxf(s_reg + t_nx.w + batt, 0.f)) * a_nx.w; \
        wsum_p += (p0 + p1) + (p2 + p3); \
        unsigned int u0 = (unsigned int)f2bf(p0) | ((unsigned int)f2bf(p1) << 16); \
        unsigned int u1 = (unsigned int)f2bf(p2) | ((unsigned int)f2bf(p3) << 16); \
        uint2 uu; uu.x = u0; uu.y = u1; \
        *(uint2*)((char*)w_s[nb] + (((rowA << 7) + (q << 3)) ^ ((rowA & 7) << 4))) = uu; \
    } while (0)

#define DOMFMA(cb) do { \
        const char* wb = (const char*)w_s[cb]; \
        const char* hb = (const char*)hpT_s[cb]; \
        int r = lane & 15; \
        int kb = (lane >> 4) << 4; \
        int swz = (r & 7) << 4; \
        short8v A0 = *(const short8v*)(wb + (((r << 7) + kb     ) ^ swz)); \
        short8v A1 = *(const short8v*)(wb + (((r << 7) + kb + 64) ^ swz)); \
        int d0 = (wv << 5) + r; \
        short8v B00 = *(const short8v*)(hb + (((d0 << 7) + kb     ) ^ swz)); \
        short8v B01 = *(const short8v*)(hb + (((d0 << 7) + kb + 64) ^ swz)); \
        short8v B10 = *(const short8v*)(hb + ((((d0 + 16) << 7) + kb     ) ^ swz)); \
        short8v B11 = *(const short8v*)(hb + ((((d0 + 16) << 7) + kb + 64) ^ swz)); \
        acc0 = __builtin_amdgcn_mfma_f32_16x16x32_bf16(A0, B00, acc0, 0, 0, 0); \
        acc1 = __builtin_amdgcn_mfma_f32_16x16x32_bf16(A0, B10, acc1, 0, 0, 0); \
        acc0 = __builtin_amdgcn_mfma_f32_16x16x32_bf16(A1, B01, acc0, 0, 0, 0); \
        acc1 = __builtin_amdgcn_mfma_f32_16x16x32_bf16(A1, B11, acc1, 0, 0, 0); \
    } while (0)

    LOADA(0);
    STAGELOAD(0);
    PHASEA(0);
    STAGEWRITE(0);
    __syncthreads();

    int cur = 0;
    #pragma unroll 2
    for (int tt = 0; tt < NT; ++tt) {
        if (tt < NT - 1) { LOADA(tt + 1); STAGELOAD(tt + 1); }
        DOMFMA(cur);
        if (tt < NT - 1) { PHASEA(cur ^ 1); STAGEWRITE(cur ^ 1); }
        __syncthreads();
        cur ^= 1;
    }

    // wsum reduce across the 16 q-lanes of each row
    {
        float v = wsum_p;
        v += __shfl_xor(v, 1, 64);
        v += __shfl_xor(v, 2, 64);
        v += __shfl_xor(v, 4, 64);
        v += __shfl_xor(v, 8, 64);
        if (q == 0) wsum_s[rowA] = v;
    }
    __syncthreads();

    // epilogue: C row = (lane>>4)*4+reg, col = lane&15 (+16n +32wv)
    {
        int r = lane & 15;
        int rloc = (lane >> 4) << 2;
        float inv0 = 1.0f / wsum_s[rloc + 0];
        float inv1 = 1.0f / wsum_s[rloc + 1];
        float inv2 = 1.0f / wsum_s[rloc + 2];
        float inv3 = 1.0f / wsum_s[rloc + 3];
        int d0 = (wv << 5) + r;
        const float* hpb = hp + (size_t)(bN + ibase) * 128;
        float* ob = out + (size_t)(bN + ibase) * 128;
        ob[(rloc + 0) * 128 + d0]      = acc0.x * inv0 + hpb[(rloc + 0) * 128 + d0];
        ob[(rloc + 1) * 128 + d0]      = acc0.y * inv1 + hpb[(rloc + 1) * 128 + d0];
        ob[(rloc + 2) * 128 + d0]      = acc0.z * inv2 + hpb[(rloc + 2) * 128 + d0];
        ob[(rloc + 3) * 128 + d0]      = acc0.w * inv3 + hpb[(rloc + 3) * 128 + d0];
        ob[(rloc + 0) * 128 + d0 + 16] = acc1.x * inv0 + hpb[(rloc + 0) * 128 + d0 + 16];
        ob[(rloc + 1) * 128 + d0 + 16] = acc1.y * inv1 + hpb[(rloc + 1) * 128 + d0 + 16];
        ob[(rloc + 2) * 128 + d0 + 16] = acc1.z * inv2 + hpb[(rloc + 2) * 128 + d0 + 16];
        ob[(rloc + 3) * 128 + d0 + 16] = acc1.w * inv3 + hpb[(rloc + 3) * 128 + d0 + 16];
    }
#undef LOADA
#undef STAGELOAD
#undef STAGEWRITE
#undef PHASEA
#undef DOMFMA
}

extern "C" void kernel_launch(void* const* d_in, const int* in_sizes, int n_in,
                              void* d_out, int out_size, void* d_ws, size_t ws_size,
                              hipStream_t stream) {
    const float* a      = (const float*)d_in[0];   // [B,N,N]
    const float* h      = (const float*)d_in[1];   // [B,N,128]
    const float* W_proj = (const float*)d_in[2];   // [128,128]
    const float* b_proj = (const float*)d_in[3];   // [128]
    const float* w_att  = (const float*)d_in[4];   // [256]
    const float* b_att  = (const float*)d_in[5];   // [1]
    float* out = (float*)d_out;

    float* hp = (float*)d_ws;                              // [B*N,128] f32
    float* s  = hp + (size_t)NB * NN * DD;                 // [B*N]
    float* t  = s + (size_t)NB * NN;                       // [B*N]
    unsigned short* hpT = (unsigned short*)(t + (size_t)NB * NN); // [B][128][N] bf16

    proj_kernel<<<256, 256, 0, stream>>>(h, W_proj, b_proj, w_att, hp, hpT, s, t);
    fused_kernel<<<1024, 256, 0, stream>>>(a, hp, hpT, s, t, b_att, out);
}

// Round 5
// 257.647 us; speedup vs baseline: 4.4595x; 1.0257x over previous
//
#include <hip/hip_runtime.h>
#include <hip/hip_bf16.h>

#define NB 8
#define NN 2048
#define DD 128
#define NT 32    // 32 j-tiles of 64

typedef __attribute__((ext_vector_type(8))) short short8v;
typedef __attribute__((ext_vector_type(4))) float f32x4;

__device__ __forceinline__ unsigned short f2bf(float x) {
    unsigned int u = __float_as_uint(x);
    u += 0x7FFFu + ((u >> 16) & 1u);
    return (unsigned short)(u >> 16);
}

// ---------- Kernel 1: hp = h@W + b ; s,t row-dots ; hpT = bf16 transpose ----------
__global__ __launch_bounds__(256) void proj_kernel(
    const float* __restrict__ h, const float* __restrict__ W,
    const float* __restrict__ bias, const float* __restrict__ watt,
    float* __restrict__ hp, unsigned short* __restrict__ hpT,
    float* __restrict__ s, float* __restrict__ t)
{
    __shared__ float Ws[64][132];
    __shared__ float hs[64][68];
    const int tid = threadIdx.x;
    const int rowbase = blockIdx.x * 64;
    const int rg = tid >> 3;        // rows 2rg, 2rg+1
    const int dg = tid & 7;         // dims dg*16..+15

    const float4* W4 = (const float4*)W;
    const float4* h4 = (const float4*)h;

    float acc[2][16];
    #pragma unroll
    for (int r = 0; r < 2; ++r)
        #pragma unroll
        for (int d = 0; d < 16; ++d) acc[r][d] = 0.f;

    for (int p = 0; p < 2; ++p) {
        #pragma unroll
        for (int q = 0; q < 8; ++q) {
            int f = tid + 256 * q;
            float4 v = W4[2048 * p + f];
            *(float4*)&Ws[f >> 5][4 * (f & 31)] = v;
        }
        #pragma unroll
        for (int q = 0; q < 4; ++q) {
            int f = tid + 256 * q;
            int r = f >> 4, c4 = f & 15;
            float4 v = h4[(size_t)(rowbase + r) * 32 + 16 * p + c4];
            *(float4*)&hs[r][4 * c4] = v;
        }
        __syncthreads();

        #pragma unroll 8
        for (int k = 0; k < 64; ++k) {
            float h0 = hs[2 * rg][k];
            float h1 = hs[2 * rg + 1][k];
            float4 w0 = *(const float4*)&Ws[k][dg * 16];
            float4 w1 = *(const float4*)&Ws[k][dg * 16 + 4];
            float4 w2 = *(const float4*)&Ws[k][dg * 16 + 8];
            float4 w3 = *(const float4*)&Ws[k][dg * 16 + 12];
            float wv[16] = {w0.x,w0.y,w0.z,w0.w, w1.x,w1.y,w1.z,w1.w,
                            w2.x,w2.y,w2.z,w2.w, w3.x,w3.y,w3.z,w3.w};
            #pragma unroll
            for (int d = 0; d < 16; ++d) {
                acc[0][d] += h0 * wv[d];
                acc[1][d] += h1 * wv[d];
            }
        }
        __syncthreads();
    }

    // bias
    const float4* b4 = (const float4*)bias;
    #pragma unroll
    for (int dq = 0; dq < 4; ++dq) {
        float4 bv = b4[dg * 4 + dq];
        #pragma unroll
        for (int r = 0; r < 2; ++r) {
            acc[r][4 * dq + 0] += bv.x;
            acc[r][4 * dq + 1] += bv.y;
            acc[r][4 * dq + 2] += bv.z;
            acc[r][4 * dq + 3] += bv.w;
        }
    }
    // store hp (f32)
    #pragma unroll
    for (int r = 0; r < 2; ++r) {
        float4* o = (float4*)(hp + (size_t)(rowbase + 2 * rg + r) * 128);
        #pragma unroll
        for (int dq = 0; dq < 4; ++dq) {
            float4 v = {acc[r][4*dq+0], acc[r][4*dq+1], acc[r][4*dq+2], acc[r][4*dq+3]};
            o[dg * 4 + dq] = v;
        }
    }
    // store hpT (bf16, transposed [b][d][j]); u32 packs j-pair (2rg, 2rg+1)
    {
        int rowpair = ((rowbase & (NN - 1)) >> 1) + rg;
        int bb = rowbase >> 11;
        unsigned int* hT32 = (unsigned int*)hpT;
        #pragma unroll
        for (int dd = 0; dd < 16; ++dd) {
            int d = dg * 16 + dd;
            unsigned int pk = (unsigned int)f2bf(acc[0][dd]) |
                              ((unsigned int)f2bf(acc[1][dd]) << 16);
            hT32[(((size_t)bb * 128 + d) << 10) + rowpair] = pk;
        }
    }
    // rowdot: s,t
    const float4* w4 = (const float4*)watt;
    float sp[2] = {0.f, 0.f}, tp[2] = {0.f, 0.f};
    #pragma unroll
    for (int q = 0; q < 4; ++q) {
        float4 wsa = w4[dg * 4 + q];
        float4 wta = w4[32 + dg * 4 + q];
        #pragma unroll
        for (int r = 0; r < 2; ++r) {
            sp[r] += acc[r][4*q+0]*wsa.x + acc[r][4*q+1]*wsa.y
                   + acc[r][4*q+2]*wsa.z + acc[r][4*q+3]*wsa.w;
            tp[r] += acc[r][4*q+0]*wta.x + acc[r][4*q+1]*wta.y
                   + acc[r][4*q+2]*wta.z + acc[r][4*q+3]*wta.w;
        }
    }
    #pragma unroll
    for (int r = 0; r < 2; ++r) {
        float v = sp[r], u = tp[r];
        v += __shfl_xor(v, 1, 64); u += __shfl_xor(u, 1, 64);
        v += __shfl_xor(v, 2, 64); u += __shfl_xor(u, 2, 64);
        v += __shfl_xor(v, 4, 64); u += __shfl_xor(u, 4, 64);
        if (dg == 0) {
            s[rowbase + 2 * rg + r] = v;
            t[rowbase + 2 * rg + r] = u;
        }
    }
}

// ---------- Kernel 2: fused  w=exp(relu(s_i+t_j+b))*a -> bf16 MFMA @hp, row-norm, +hp ----
// 1024 blocks (B x N/16), 256 thr (4 waves). 16 rows/block, JT=64, 32 tiles.
// B-operand (hpT) loaded global->reg per-lane, 2 tiles deep. a/t 2 tiles deep.
// Only w goes through LDS (4 KB dbuf, XOR-swizzled). 1 barrier per tile.
__global__ __launch_bounds__(256, 4) void fused_kernel(
    const float* __restrict__ a, const float* __restrict__ hp,
    const unsigned short* __restrict__ hpT,
    const float* __restrict__ s, const float* __restrict__ t,
    const float* __restrict__ battp, float* __restrict__ out)
{
    __shared__ unsigned short w_s[2][16 * 64];
    __shared__ float wsum_s[16];

    const int tid  = threadIdx.x;
    const int lane = tid & 63;
    const int wv   = tid >> 6;
    const int b     = blockIdx.x >> 7;
    const int ibase = (blockIdx.x & 127) * 16;
    const int bN    = b * NN;

    const int rowA = tid >> 4;          // phase A row 0..15
    const int q    = tid & 15;          // phase A j-quad: j = 4q..4q+3

    const int r  = lane & 15;           // MFMA fragment row/col index
    const int kg = lane >> 4;           // 0..3 k-group
    const int d0 = (wv << 5) + r;

    const float batt = battp[0];
    const float4* a4 = (const float4*)a;
    const float4* t4 = (const float4*)t;
    const float s_reg = s[bN + ibase + rowA];
    const size_t arow = (size_t)(bN + ibase + rowA) * 512;

    // per-lane B-operand base pointers (shorts): row d, k-slice kg
    const unsigned short* pB0 = hpT + (((size_t)(b * 128 + d0)) << 11) + (kg << 3);
    const unsigned short* pB1 = pB0 + ((size_t)16 << 11);

    float wsum_p = 0.f;
    f32x4 acc0 = {0.f, 0.f, 0.f, 0.f};
    f32x4 acc1 = {0.f, 0.f, 0.f, 0.f};

    float4 av[2], tv[2];
    short8v B00[2], B01[2], B10[2], B11[2];

#define LOADAT(P, k) do { \
        av[P] = a4[arow + (k) * 16 + q]; \
        tv[P] = t4[(bN >> 2) + (k) * 16 + q]; \
    } while (0)

#define LOADB(P, k) do { \
        const short8v* b0 = (const short8v*)(pB0 + (k) * 64); \
        const short8v* b1 = (const short8v*)(pB1 + (k) * 64); \
        B00[P] = b0[0]; B01[P] = b0[4]; \
        B10[P] = b1[0]; B11[P] = b1[4]; \
    } while (0)

#define PHASEA(P) do { \
        float p0 = __expf(fmaxf(s_reg + tv[P].x + batt, 0.f)) * av[P].x; \
        float p1 = __expf(fmaxf(s_reg + tv[P].y + batt, 0.f)) * av[P].y; \
        float p2 = __expf(fmaxf(s_reg + tv[P].z + batt, 0.f)) * av[P].z; \
        float p3 = __expf(fmaxf(s_reg + tv[P].w + batt, 0.f)) * av[P].w; \
        wsum_p += (p0 + p1) + (p2 + p3); \
        unsigned int u0 = (unsigned int)f2bf(p0) | ((unsigned int)f2bf(p1) << 16); \
        unsigned int u1 = (unsigned int)f2bf(p2) | ((unsigned int)f2bf(p3) << 16); \
        uint2 uu; uu.x = u0; uu.y = u1; \
        *(uint2*)((char*)w_s[P] + (((rowA << 7) + (q << 3)) ^ ((rowA & 7) << 4))) = uu; \
    } while (0)

#define DOMFMA(P) do { \
        const char* wb = (const char*)w_s[P]; \
        int kbB = kg << 4; \
        int swz = (r & 7) << 4; \
        short8v A0 = *(const short8v*)(wb + (((r << 7) + kbB     ) ^ swz)); \
        short8v A1 = *(const short8v*)(wb + (((r << 7) + kbB + 64) ^ swz)); \
        acc0 = __builtin_amdgcn_mfma_f32_16x16x32_bf16(A0, B00[P], acc0, 0, 0, 0); \
        acc1 = __builtin_amdgcn_mfma_f32_16x16x32_bf16(A0, B10[P], acc1, 0, 0, 0); \
        acc0 = __builtin_amdgcn_mfma_f32_16x16x32_bf16(A1, B01[P], acc0, 0, 0, 0); \
        acc1 = __builtin_amdgcn_mfma_f32_16x16x32_bf16(A1, B11[P], acc1, 0, 0, 0); \
    } while (0)

    // prologue: tiles 0,1 in flight
    LOADAT(0, 0); LOADB(0, 0);
    LOADAT(1, 1); LOADB(1, 1);
    PHASEA(0);                    // w for tile 0 -> w_s[0]
    __syncthreads();

    for (int tt = 0; tt < NT; tt += 2) {
        // ---- tile tt (parity 0) ----
        PHASEA(1);                              // w for tile tt+1 (av[1] 1 tile in flight)
        if (tt + 2 < NT) LOADAT(0, tt + 2);     // av[0] freed by PHASEA(0) last tile
        DOMFMA(0);                              // consumes B*[0] (2 tiles in flight)
        if (tt + 2 < NT) LOADB(0, tt + 2);      // B*[0] just freed
        __syncthreads();
        // ---- tile tt+1 (parity 1) ----
        if (tt + 2 < NT) PHASEA(0);             // w for tile tt+2
        if (tt + 3 < NT) LOADAT(1, tt + 3);
        DOMFMA(1);
        if (tt + 3 < NT) LOADB(1, tt + 3);
        __syncthreads();
    }

    // wsum reduce across the 16 q-lanes of each row
    {
        float v = wsum_p;
        v += __shfl_xor(v, 1, 64);
        v += __shfl_xor(v, 2, 64);
        v += __shfl_xor(v, 4, 64);
        v += __shfl_xor(v, 8, 64);
        if (q == 0) wsum_s[rowA] = v;
    }
    __syncthreads();

    // epilogue: C row = (lane>>4)*4+reg, col = lane&15 (d = d0, d0+16)
    {
        int rloc = (lane >> 4) << 2;
        float inv0 = 1.0f / wsum_s[rloc + 0];
        float inv1 = 1.0f / wsum_s[rloc + 1];
        float inv2 = 1.0f / wsum_s[rloc + 2];
        float inv3 = 1.0f / wsum_s[rloc + 3];
        const float* hpb = hp + (size_t)(bN + ibase) * 128;
        float* ob = out + (size_t)(bN + ibase) * 128;
        ob[(rloc + 0) * 128 + d0]      = acc0.x * inv0 + hpb[(rloc + 0) * 128 + d0];
        ob[(rloc + 1) * 128 + d0]      = acc0.y * inv1 + hpb[(rloc + 1) * 128 + d0];
        ob[(rloc + 2) * 128 + d0]      = acc0.z * inv2 + hpb[(rloc + 2) * 128 + d0];
        ob[(rloc + 3) * 128 + d0]      = acc0.w * inv3 + hpb[(rloc + 3) * 128 + d0];
        ob[(rloc + 0) * 128 + d0 + 16] = acc1.x * inv0 + hpb[(rloc + 0) * 128 + d0 + 16];
        ob[(rloc + 1) * 128 + d0 + 16] = acc1.y * inv1 + hpb[(rloc + 1) * 128 + d0 + 16];
        ob[(rloc + 2) * 128 + d0 + 16] = acc1.z * inv2 + hpb[(rloc + 2) * 128 + d0 + 16];
        ob[(rloc + 3) * 128 + d0 + 16] = acc1.w * inv3 + hpb[(rloc + 3) * 128 + d0 + 16];
    }
#undef LOADAT
#undef LOADB
#undef PHASEA
#undef DOMFMA
}

extern "C" void kernel_launch(void* const* d_in, const int* in_sizes, int n_in,
                              void* d_out, int out_size, void* d_ws, size_t ws_size,
                              hipStream_t stream) {
    const float* a      = (const float*)d_in[0];   // [B,N,N]
    const float* h      = (const float*)d_in[1];   // [B,N,128]
    const float* W_proj = (const float*)d_in[2];   // [128,128]
    const float* b_proj = (const float*)d_in[3];   // [128]
    const float* w_att  = (const float*)d_in[4];   // [256]
    const float* b_att  = (const float*)d_in[5];   // [1]
    float* out = (float*)d_out;

    float* hp = (float*)d_ws;                              // [B*N,128] f32
    float* s  = hp + (size_t)NB * NN * DD;                 // [B*N]
    float* t  = s + (size_t)NB * NN;                       // [B*N]
    unsigned short* hpT = (unsigned short*)(t + (size_t)NB * NN); // [B][128][N] bf16

    proj_kernel<<<256, 256, 0, stream>>>(h, W_proj, b_proj, w_att, hp, hpT, s, t);
    fused_kernel<<<1024, 256, 0, stream>>>(a, hp, hpT, s, t, b_att, out);
}